// Round 1
// baseline (242.595 us; speedup 1.0000x reference)
//
#include <hip/hip_runtime.h>
#include <hip/hip_bf16.h>
#include <stdint.h>

typedef __attribute__((ext_vector_type(8))) short short8;
typedef __attribute__((ext_vector_type(4))) short short4v;
typedef __attribute__((ext_vector_type(4))) float f32x4;
typedef __attribute__((ext_vector_type(4))) float float4v;

#define LOG2E_OVER8 0.18033688011112042f  // (1/8)*log2(e), folded into Q

__device__ __forceinline__ short bf16r(float f) {  // f32 -> bf16 RNE
  union { float f; uint32_t u; } v; v.f = f;
  uint32_t r = (v.u + 0x7FFFu + ((v.u >> 16) & 1u)) >> 16;
  return (short)r;
}

__device__ __forceinline__ void gload16(const void* g, void* l) {
  __builtin_amdgcn_global_load_lds((const __attribute__((address_space(1))) void*)g,
                                   (__attribute__((address_space(3))) void*)l, 16, 0, 0);
}

// ---------------- elementwise f32 -> bf16 (x, wo) ----------------
__global__ void k_cvt(const float* __restrict__ in, short* __restrict__ out, int n4) {
  int i = blockIdx.x * 256 + threadIdx.x;
  if (i >= n4) return;
  float4v v = *(const float4v*)(in + (size_t)i * 4);
  short4v o = { bf16r(v[0]), bf16r(v[1]), bf16r(v[2]), bf16r(v[3]) };
  *(short4v*)(out + (size_t)i * 4) = o;
}

// ---------------- wq/wk/wv [16][1024][64] -> Wt [3072][1024] bf16 (B^T layout) ----------------
__global__ void k_cvt_wt(const float* __restrict__ wq, const float* __restrict__ wk,
                         const float* __restrict__ wv, short* __restrict__ wt) {
  __shared__ short tile[64][65];
  int kt = blockIdx.x, h = blockIdx.y, wsel = blockIdx.z;
  const float* src = wsel == 0 ? wq : (wsel == 1 ? wk : wv);
  int tid = threadIdx.x;
  {
    int e = tid & 63, r4 = tid >> 6;
#pragma unroll
    for (int p = 0; p < 16; ++p) {
      int kk = p * 4 + r4;
      tile[kk][e] = bf16r(src[h * 65536 + (kt * 64 + kk) * 64 + e]);
    }
  }
  __syncthreads();
  {
    int kk = tid & 63, r4 = tid >> 6;
#pragma unroll
    for (int p = 0; p < 16; ++p) {
      int e = p * 4 + r4;
      wt[(size_t)(wsel * 1024 + h * 64 + e) * 1024 + kt * 64 + kk] = tile[kk][e];
    }
  }
}

// ---------------- V [bh][s][64] -> Vt [bh][64][2048] bf16 ----------------
__global__ void k_vt(const short* __restrict__ vb, short* __restrict__ vt) {
  __shared__ short tile[64][65];
  int st = blockIdx.x, bh = blockIdx.y;
  int tid = threadIdx.x;
  {
    int e = tid & 63, r4 = tid >> 6;
#pragma unroll
    for (int p = 0; p < 16; ++p) {
      int ss = p * 4 + r4;
      tile[ss][e] = vb[(size_t)(bh * 2048 + st * 64 + ss) * 64 + e];
    }
  }
  __syncthreads();
  {
    int ss = tid & 63, r4 = tid >> 6;
#pragma unroll
    for (int p = 0; p < 16; ++p) {
      int e = p * 4 + r4;
      vt[(size_t)(bh * 64 + e) * 2048 + st * 64 + ss] = tile[ss][e];
    }
  }
}

// ---------------- GEMM: C[m][n] = sum_k A[m][k]*Bt[n][k], K=1024, tile 128x128, BK=32 ----------------
// EPI=0: QKV epilogue (bias + scale, scatter to q/k/v [bh][s][64] bf16)
// EPI=1: out-proj epilogue (+bo, fp32 store)
template<int EPI>
__global__ __launch_bounds__(256, 2) void k_gemm(
    const short* __restrict__ A, const short* __restrict__ Bt,
    const float* __restrict__ b0, const float* __restrict__ b1, const float* __restrict__ b2,
    short* __restrict__ qb, short* __restrict__ kb, short* __restrict__ vb,
    float* __restrict__ outp) {
  __shared__ short As[2][128 * 32];
  __shared__ short Bs[2][128 * 32];
  int tid = threadIdx.x;
  int l = tid & 63, w = tid >> 6;
  int g = l >> 4, c = l & 15;
  int wm = w >> 1, wn = w & 1;
  int m0 = blockIdx.y * 128, n0 = blockIdx.x * 128;

  f32x4 acc[4][4];
#pragma unroll
  for (int i = 0; i < 4; ++i)
#pragma unroll
    for (int j = 0; j < 4; ++j) acc[i][j] = (f32x4){0.f, 0.f, 0.f, 0.f};

  // stage: 512 16B-chunks per operand; chunk ch -> row=ch>>2, stored blk=ch&3,
  // source blk = stored ^ ((row>>1)&3)   (bank-conflict swizzle, LDS stays linear)
  auto stage = [&](int buf, int kt) {
#pragma unroll
    for (int i = 0; i < 2; ++i) {
      int ch = w * 128 + i * 64 + l;
      int row = ch >> 2, cbs = ch & 3;
      int sb = cbs ^ ((row >> 1) & 3);
      gload16(A + (size_t)(m0 + row) * 1024 + kt * 32 + sb * 8,
              &As[buf][(w * 128 + i * 64) * 8]);
      gload16(Bt + (size_t)(n0 + row) * 1024 + kt * 32 + sb * 8,
              &Bs[buf][(w * 128 + i * 64) * 8]);
    }
  };

  stage(0, 0);
  __syncthreads();
  for (int kt = 0; kt < 32; ++kt) {
    int buf = kt & 1;
    if (kt + 1 < 32) stage(buf ^ 1, kt + 1);
    short8 af[4], bfr[4];
#pragma unroll
    for (int mi = 0; mi < 4; ++mi) {
      int row = wm * 64 + mi * 16 + c;
      int blk = g ^ ((row >> 1) & 3);
      af[mi] = *(const short8*)&As[buf][row * 32 + blk * 8];
    }
#pragma unroll
    for (int ni = 0; ni < 4; ++ni) {
      int row = wn * 64 + ni * 16 + c;
      int blk = g ^ ((row >> 1) & 3);
      bfr[ni] = *(const short8*)&Bs[buf][row * 32 + blk * 8];
    }
#pragma unroll
    for (int mi = 0; mi < 4; ++mi)
#pragma unroll
      for (int ni = 0; ni < 4; ++ni)
        acc[mi][ni] = __builtin_amdgcn_mfma_f32_16x16x32_bf16(af[mi], bfr[ni], acc[mi][ni], 0, 0, 0);
    __syncthreads();
  }

#pragma unroll
  for (int mi = 0; mi < 4; ++mi)
#pragma unroll
    for (int ni = 0; ni < 4; ++ni) {
      int n = n0 + wn * 64 + ni * 16 + c;
      if (EPI == 0) {
        int sel = n >> 10, nn = n & 1023;
        int h = nn >> 6, e = nn & 63;
        const float* bp = sel == 0 ? b0 : (sel == 1 ? b1 : b2);
        short* dst = sel == 0 ? qb : (sel == 1 ? kb : vb);
        float bias = bp[nn];
        float sc = (sel == 0) ? LOG2E_OVER8 : 1.0f;
#pragma unroll
        for (int r = 0; r < 4; ++r) {
          int m = m0 + wm * 64 + mi * 16 + g * 4 + r;
          int b = m >> 11, s = m & 2047;
          float v = (acc[mi][ni][r] + bias) * sc;
          dst[(size_t)((b * 16 + h) * 2048 + s) * 64 + e] = bf16r(v);
        }
      } else {
        float bias = b0[n];
#pragma unroll
        for (int r = 0; r < 4; ++r) {
          int m = m0 + wm * 64 + mi * 16 + g * 4 + r;
          outp[(size_t)m * 1024 + n] = acc[mi][ni][r] + bias;
        }
      }
    }
}

// ---------------- flash attention ----------------
// block: 4 waves x 32 Q-rows = 128-row Q tile; KV tile 64, double-buffered LDS.
// Swapped QK^T (S^T = mfma(K,Q)) -> per-lane k-local P; PV via k-permute trick:
// P fed from registers, V^T fragments from swizzled LDS (2x ds_read_b64 each).
__global__ __launch_bounds__(256, 2) void k_attn(
    const short* __restrict__ Qb, const short* __restrict__ Kb,
    const short* __restrict__ Vt, short* __restrict__ attb) {
  __shared__ short Ks[2][64 * 64];
  __shared__ short Vs[2][64 * 64];
  int tid = threadIdx.x;
  int l = tid & 63, w = tid >> 6;
  int g = l >> 4, c = l & 15;
  int qt = blockIdx.x, bh = blockIdx.y;
  int q0 = qt * 128 + w * 32;

  // Q fragments (B-operand of S^T): lane holds Q[q0+qi*16+c][es*32+g*8 .. +7]
  const short* Qh = Qb + (size_t)bh * 2048 * 64;
  short8 qf[2][2];
#pragma unroll
  for (int qi = 0; qi < 2; ++qi)
#pragma unroll
    for (int es = 0; es < 2; ++es)
      qf[qi][es] = *(const short8*)&Qh[(size_t)(q0 + qi * 16 + c) * 64 + es * 32 + g * 8];

  f32x4 oacc[4][2];
#pragma unroll
  for (int i = 0; i < 4; ++i) {
    oacc[i][0] = (f32x4){0.f, 0.f, 0.f, 0.f};
    oacc[i][1] = (f32x4){0.f, 0.f, 0.f, 0.f};
  }
  float mrun[2] = {-3e38f, -3e38f};
  float lrun[2] = {0.f, 0.f};

  auto stageKV = [&](int buf, int t0) {
#pragma unroll
    for (int i = 0; i < 2; ++i) {
      int ch = w * 128 + i * 64 + l;
      int row = ch >> 3, cbs = ch & 7;
      int sb = cbs ^ (row & 7);  // pre-swizzled source, linear LDS dest
      gload16(Kb + (size_t)(bh * 2048 + t0 + row) * 64 + sb * 8,
              &Ks[buf][(w * 128 + i * 64) * 8]);
      gload16(Vt + (size_t)(bh * 64 + row) * 2048 + t0 + sb * 8,
              &Vs[buf][(w * 128 + i * 64) * 8]);
    }
  };

  stageKV(0, 0);
  __syncthreads();

  for (int t = 0; t < 32; ++t) {
    int buf = t & 1;
    if (t + 1 < 32) stageKV(buf ^ 1, (t + 1) * 64);

    // ---- S^T = K * Q^T : D[k][q], k in tile (64), q in wave rows (32) ----
    f32x4 sacc[4][2];
#pragma unroll
    for (int i = 0; i < 4; ++i) {
      sacc[i][0] = (f32x4){0.f, 0.f, 0.f, 0.f};
      sacc[i][1] = (f32x4){0.f, 0.f, 0.f, 0.f};
    }
#pragma unroll
    for (int es = 0; es < 2; ++es) {
      short8 kf[4];
#pragma unroll
      for (int mi = 0; mi < 4; ++mi) {
        int row = mi * 16 + c;
        int blk = (es * 4 + g) ^ (row & 7);
        kf[mi] = *(const short8*)&Ks[buf][row * 64 + blk * 8];
      }
#pragma unroll
      for (int mi = 0; mi < 4; ++mi)
#pragma unroll
        for (int qi = 0; qi < 2; ++qi)
          sacc[mi][qi] = __builtin_amdgcn_mfma_f32_16x16x32_bf16(kf[mi], qf[qi][es], sacc[mi][qi], 0, 0, 0);
    }

    // ---- online softmax over k (rows of S^T): lane-local 16 vals + shfl over g ----
    float p[4][2][4];
    float fac[2];
#pragma unroll
    for (int qi = 0; qi < 2; ++qi) {
      float mx = -3e38f;
#pragma unroll
      for (int mi = 0; mi < 4; ++mi)
#pragma unroll
        for (int r = 0; r < 4; ++r) mx = fmaxf(mx, sacc[mi][qi][r]);
      mx = fmaxf(mx, __shfl_xor(mx, 16));
      mx = fmaxf(mx, __shfl_xor(mx, 32));
      float mnew = fmaxf(mrun[qi], mx);
      float f = __builtin_amdgcn_exp2f(mrun[qi] - mnew);
      float sum = 0.f;
#pragma unroll
      for (int mi = 0; mi < 4; ++mi)
#pragma unroll
        for (int r = 0; r < 4; ++r) {
          float pv = __builtin_amdgcn_exp2f(sacc[mi][qi][r] - mnew);
          p[mi][qi][r] = pv;
          sum += pv;
        }
      sum += __shfl_xor(sum, 16);
      sum += __shfl_xor(sum, 32);
      lrun[qi] = lrun[qi] * f + sum;
      mrun[qi] = mnew;
      fac[qi] = f;
    }
#pragma unroll
    for (int ei = 0; ei < 4; ++ei)
#pragma unroll
      for (int qi = 0; qi < 2; ++qi)
#pragma unroll
        for (int r = 0; r < 4; ++r) oacc[ei][qi][r] *= fac[qi];

    // ---- pack P (B-operand, permuted k): j=0..3 <- sacc-row mi=ks*2, j=4..7 <- mi=ks*2+1 ----
    short8 pf[2][2];
#pragma unroll
    for (int qi = 0; qi < 2; ++qi)
#pragma unroll
      for (int ks = 0; ks < 2; ++ks) {
        short8 v;
#pragma unroll
        for (int j = 0; j < 4; ++j) v[j] = bf16r(p[ks * 2][qi][j]);
#pragma unroll
        for (int j = 0; j < 4; ++j) v[4 + j] = bf16r(p[ks * 2 + 1][qi][j]);
        pf[qi][ks] = v;
      }

    // ---- PV: att^T[e][q] += V^T-frag (matching k-permute) * P-frag ----
#pragma unroll
    for (int ks = 0; ks < 2; ++ks)
#pragma unroll
      for (int ei = 0; ei < 4; ++ei) {
        int row = ei * 16 + c;  // e-row of Vt tile
        int blk0 = (ks * 4 + (g >> 1)) ^ (row & 7);
        short4v v0 = *(const short4v*)&Vs[buf][row * 64 + blk0 * 8 + (g & 1) * 4];
        int blk1 = (ks * 4 + 2 + (g >> 1)) ^ (row & 7);
        short4v v1 = *(const short4v*)&Vs[buf][row * 64 + blk1 * 8 + (g & 1) * 4];
        short8 vf = {v0[0], v0[1], v0[2], v0[3], v1[0], v1[1], v1[2], v1[3]};
#pragma unroll
        for (int qi = 0; qi < 2; ++qi)
          oacc[ei][qi] = __builtin_amdgcn_mfma_f32_16x16x32_bf16(vf, pf[qi][ks], oacc[ei][qi], 0, 0, 0);
      }

    __syncthreads();
  }

  // ---- epilogue: normalize, write att[b][s][h*64+e] bf16 (A of out-proj) ----
  int b = bh >> 4, h = bh & 15;
#pragma unroll
  for (int qi = 0; qi < 2; ++qi) {
    float inv = 1.0f / lrun[qi];
    int s = q0 + qi * 16 + c;
#pragma unroll
    for (int ei = 0; ei < 4; ++ei) {
      short4v o;
#pragma unroll
      for (int r = 0; r < 4; ++r) o[r] = bf16r(oacc[ei][qi][r] * inv);
      *(short4v*)&attb[(size_t)(b * 2048 + s) * 1024 + h * 64 + ei * 16 + g * 4] = o;
    }
  }
}

extern "C" void kernel_launch(void* const* d_in, const int* in_sizes, int n_in,
                              void* d_out, int out_size, void* d_ws, size_t ws_size,
                              hipStream_t stream) {
  const float* x  = (const float*)d_in[0];
  const float* wq = (const float*)d_in[1];
  const float* bq = (const float*)d_in[2];
  const float* wk = (const float*)d_in[3];
  const float* bk = (const float*)d_in[4];
  const float* wv = (const float*)d_in[5];
  const float* bv = (const float*)d_in[6];
  const float* wo = (const float*)d_in[7];
  const float* bo = (const float*)d_in[8];
  float* out = (float*)d_out;

  uint8_t* ws = (uint8_t*)d_ws;
  short* xb  = (short*)(ws);                  // 16 MB: x bf16 (reused as att after QKV GEMM)
  short* wt  = (short*)(ws + (16u << 20));    // 6 MB : Wt_qkv
  short* wob = (short*)(ws + (22u << 20));    // 2 MB : wo bf16
  short* qb  = (short*)(ws + (24u << 20));    // 16 MB: Q (scaled) [bh][s][64]
  short* kb  = (short*)(ws + (40u << 20));    // 16 MB: K [bh][s][64]
  short* vb  = (short*)(ws + (56u << 20));    // 16 MB: V [bh][s][64]
  short* vtb = (short*)(ws + (72u << 20));    // 16 MB: V^T [bh][64][2048]  (total 88 MB)
  short* attb = xb;                           // alias: x dead after QKV GEMM

  k_cvt<<<8192, 256, 0, stream>>>(x, xb, 2097152);
  k_cvt<<<1024, 256, 0, stream>>>(wo, wob, 262144);
  k_cvt_wt<<<dim3(16, 16, 3), 256, 0, stream>>>(wq, wk, wv, wt);
  k_gemm<0><<<dim3(24, 64), 256, 0, stream>>>(xb, wt, bq, bk, bv, qb, kb, vb, nullptr);
  k_vt<<<dim3(32, 64), 256, 0, stream>>>(vb, vtb);
  k_attn<<<dim3(16, 64), 256, 0, stream>>>(qb, kb, vtb, attb);
  k_gemm<1><<<dim3(8, 64), 256, 0, stream>>>(attb, wob, bo, nullptr, nullptr,
                                             nullptr, nullptr, nullptr, out);
}

// Round 2
// 227.990 us; speedup vs baseline: 1.0641x; 1.0641x over previous
//
#include <hip/hip_runtime.h>
#include <hip/hip_bf16.h>
#include <stdint.h>

typedef __attribute__((ext_vector_type(8))) short short8;
typedef __attribute__((ext_vector_type(4))) short short4v;
typedef __attribute__((ext_vector_type(4))) float f32x4;
typedef __attribute__((ext_vector_type(4))) float float4v;

#define LOG2E_OVER8 0.18033688011112042f  // (1/8)*log2(e), folded into Q

__device__ __forceinline__ short bf16r(float f) {  // f32 -> bf16 RNE
  union { float f; uint32_t u; } v; v.f = f;
  uint32_t r = (v.u + 0x7FFFu + ((v.u >> 16) & 1u)) >> 16;
  return (short)r;
}

__device__ __forceinline__ void gload16(const void* g, void* l) {
  __builtin_amdgcn_global_load_lds((const __attribute__((address_space(1))) void*)g,
                                   (__attribute__((address_space(3))) void*)l, 16, 0, 0);
}

// ---------------- elementwise f32 -> bf16 (x, wo) ----------------
__global__ void k_cvt(const float* __restrict__ in, short* __restrict__ out, int n4) {
  int i = blockIdx.x * 256 + threadIdx.x;
  if (i >= n4) return;
  float4v v = *(const float4v*)(in + (size_t)i * 4);
  short4v o = { bf16r(v[0]), bf16r(v[1]), bf16r(v[2]), bf16r(v[3]) };
  *(short4v*)(out + (size_t)i * 4) = o;
}

// ---------------- wq/wk/wv [16][1024][64] -> Wt [3072][1024] bf16 (B^T layout) ----------------
__global__ void k_cvt_wt(const float* __restrict__ wq, const float* __restrict__ wk,
                         const float* __restrict__ wv, short* __restrict__ wt) {
  __shared__ short tile[64][65];
  int kt = blockIdx.x, h = blockIdx.y, wsel = blockIdx.z;
  const float* src = wsel == 0 ? wq : (wsel == 1 ? wk : wv);
  int tid = threadIdx.x;
  {
    int e = tid & 63, r4 = tid >> 6;
#pragma unroll
    for (int p = 0; p < 16; ++p) {
      int kk = p * 4 + r4;
      tile[kk][e] = bf16r(src[h * 65536 + (kt * 64 + kk) * 64 + e]);
    }
  }
  __syncthreads();
  {
    int kk = tid & 63, r4 = tid >> 6;
#pragma unroll
    for (int p = 0; p < 16; ++p) {
      int e = p * 4 + r4;
      wt[(size_t)(wsel * 1024 + h * 64 + e) * 1024 + kt * 64 + kk] = tile[kk][e];
    }
  }
}

// ---------------- V [bh][s][64] -> Vt [bh][64][2048] bf16 ----------------
__global__ void k_vt(const short* __restrict__ vb, short* __restrict__ vt) {
  __shared__ short tile[64][65];
  int st = blockIdx.x, bh = blockIdx.y;
  int tid = threadIdx.x;
  {
    int e = tid & 63, r4 = tid >> 6;
#pragma unroll
    for (int p = 0; p < 16; ++p) {
      int ss = p * 4 + r4;
      tile[ss][e] = vb[(size_t)(bh * 2048 + st * 64 + ss) * 64 + e];
    }
  }
  __syncthreads();
  {
    int ss = tid & 63, r4 = tid >> 6;
#pragma unroll
    for (int p = 0; p < 16; ++p) {
      int e = p * 4 + r4;
      vt[(size_t)(bh * 64 + e) * 2048 + st * 64 + ss] = tile[ss][e];
    }
  }
}

// ---------------- GEMM: C[m][n] = sum_k A[m][k]*Bt[n][k], K=1024, tile 128x128, BK=32 ----------------
template<int EPI>
__global__ __launch_bounds__(256, 2) void k_gemm(
    const short* __restrict__ A, const short* __restrict__ Bt,
    const float* __restrict__ b0, const float* __restrict__ b1, const float* __restrict__ b2,
    short* __restrict__ qb, short* __restrict__ kb, short* __restrict__ vb,
    float* __restrict__ outp) {
  __shared__ short As[2][128 * 32];
  __shared__ short Bs[2][128 * 32];
  int tid = threadIdx.x;
  int l = tid & 63, w = tid >> 6;
  int g = l >> 4, c = l & 15;
  int wm = w >> 1, wn = w & 1;
  int m0 = blockIdx.y * 128, n0 = blockIdx.x * 128;

  f32x4 acc[4][4];
#pragma unroll
  for (int i = 0; i < 4; ++i)
#pragma unroll
    for (int j = 0; j < 4; ++j) acc[i][j] = (f32x4){0.f, 0.f, 0.f, 0.f};

  auto stage = [&](int buf, int kt) {
#pragma unroll
    for (int i = 0; i < 2; ++i) {
      int ch = w * 128 + i * 64 + l;
      int row = ch >> 2, cbs = ch & 3;
      int sb = cbs ^ ((row >> 1) & 3);
      gload16(A + (size_t)(m0 + row) * 1024 + kt * 32 + sb * 8,
              &As[buf][(w * 128 + i * 64) * 8]);
      gload16(Bt + (size_t)(n0 + row) * 1024 + kt * 32 + sb * 8,
              &Bs[buf][(w * 128 + i * 64) * 8]);
    }
  };

  stage(0, 0);
  __syncthreads();
  for (int kt = 0; kt < 32; ++kt) {
    int buf = kt & 1;
    if (kt + 1 < 32) stage(buf ^ 1, kt + 1);
    short8 af[4], bfr[4];
#pragma unroll
    for (int mi = 0; mi < 4; ++mi) {
      int row = wm * 64 + mi * 16 + c;
      int blk = g ^ ((row >> 1) & 3);
      af[mi] = *(const short8*)&As[buf][row * 32 + blk * 8];
    }
#pragma unroll
    for (int ni = 0; ni < 4; ++ni) {
      int row = wn * 64 + ni * 16 + c;
      int blk = g ^ ((row >> 1) & 3);
      bfr[ni] = *(const short8*)&Bs[buf][row * 32 + blk * 8];
    }
#pragma unroll
    for (int mi = 0; mi < 4; ++mi)
#pragma unroll
      for (int ni = 0; ni < 4; ++ni)
        acc[mi][ni] = __builtin_amdgcn_mfma_f32_16x16x32_bf16(af[mi], bfr[ni], acc[mi][ni], 0, 0, 0);
    __syncthreads();
  }

#pragma unroll
  for (int mi = 0; mi < 4; ++mi)
#pragma unroll
    for (int ni = 0; ni < 4; ++ni) {
      int n = n0 + wn * 64 + ni * 16 + c;
      if (EPI == 0) {
        int sel = n >> 10, nn = n & 1023;
        int h = nn >> 6, e = nn & 63;
        const float* bp = sel == 0 ? b0 : (sel == 1 ? b1 : b2);
        short* dst = sel == 0 ? qb : (sel == 1 ? kb : vb);
        float bias = bp[nn];
        float sc = (sel == 0) ? LOG2E_OVER8 : 1.0f;
#pragma unroll
        for (int r = 0; r < 4; ++r) {
          int m = m0 + wm * 64 + mi * 16 + g * 4 + r;
          int b = m >> 11, s = m & 2047;
          float v = (acc[mi][ni][r] + bias) * sc;
          dst[(size_t)((b * 16 + h) * 2048 + s) * 64 + e] = bf16r(v);
        }
      } else {
        float bias = b0[n];
#pragma unroll
        for (int r = 0; r < 4; ++r) {
          int m = m0 + wm * 64 + mi * 16 + g * 4 + r;
          outp[(size_t)m * 1024 + n] = acc[mi][ni][r] + bias;
        }
      }
    }
}

// ---------------- flash attention ----------------
// 4 waves x 32 Q-rows; KV tile 64, double-buffered LDS. Swapped QK^T (S^T=mfma(K,Q)).
// VALU diet: zero-reg C for first QK slice, cvt_pk P-pack, defer-max rescale, setprio.
__global__ __launch_bounds__(256, 2) void k_attn(
    const short* __restrict__ Qb, const short* __restrict__ Kb,
    const short* __restrict__ Vt, short* __restrict__ attb) {
  __shared__ short Ks[2][64 * 64];
  __shared__ short Vs[2][64 * 64];
  int tid = threadIdx.x;
  int l = tid & 63, w = tid >> 6;
  int g = l >> 4, c = l & 15;
  int qt = blockIdx.x, bh = blockIdx.y;
  int q0 = qt * 128 + w * 32;

  const short* Qh = Qb + (size_t)bh * 2048 * 64;
  short8 qf[2][2];
#pragma unroll
  for (int qi = 0; qi < 2; ++qi)
#pragma unroll
    for (int es = 0; es < 2; ++es)
      qf[qi][es] = *(const short8*)&Qh[(size_t)(q0 + qi * 16 + c) * 64 + es * 32 + g * 8];

  const f32x4 z4 = (f32x4){0.f, 0.f, 0.f, 0.f};
  f32x4 oacc[4][2];
#pragma unroll
  for (int i = 0; i < 4; ++i) {
    oacc[i][0] = z4;
    oacc[i][1] = z4;
  }
  float mrun[2] = {-3e38f, -3e38f};
  float lrun[2] = {0.f, 0.f};

  auto stageKV = [&](int buf, int t0) {
#pragma unroll
    for (int i = 0; i < 2; ++i) {
      int ch = w * 128 + i * 64 + l;
      int row = ch >> 3, cbs = ch & 7;
      int sb = cbs ^ (row & 7);
      gload16(Kb + (size_t)(bh * 2048 + t0 + row) * 64 + sb * 8,
              &Ks[buf][(w * 128 + i * 64) * 8]);
      gload16(Vt + (size_t)(bh * 64 + row) * 2048 + t0 + sb * 8,
              &Vs[buf][(w * 128 + i * 64) * 8]);
    }
  };

  stageKV(0, 0);
  __syncthreads();

  for (int t = 0; t < 32; ++t) {
    int buf = t & 1;
    if (t + 1 < 32) stageKV(buf ^ 1, (t + 1) * 64);

    // ---- S^T = K * Q^T ----
    short8 kf0[4], kf1[4];
#pragma unroll
    for (int mi = 0; mi < 4; ++mi) {
      int row = mi * 16 + c;
      kf0[mi] = *(const short8*)&Ks[buf][row * 64 + (g ^ (row & 7)) * 8];
      kf1[mi] = *(const short8*)&Ks[buf][row * 64 + ((4 + g) ^ (row & 7)) * 8];
    }
    f32x4 sacc[4][2];
    __builtin_amdgcn_s_setprio(1);
#pragma unroll
    for (int mi = 0; mi < 4; ++mi)
#pragma unroll
      for (int qi = 0; qi < 2; ++qi)
        sacc[mi][qi] = __builtin_amdgcn_mfma_f32_16x16x32_bf16(kf0[mi], qf[qi][0], z4, 0, 0, 0);
#pragma unroll
    for (int mi = 0; mi < 4; ++mi)
#pragma unroll
      for (int qi = 0; qi < 2; ++qi)
        sacc[mi][qi] = __builtin_amdgcn_mfma_f32_16x16x32_bf16(kf1[mi], qf[qi][1], sacc[mi][qi], 0, 0, 0);
    __builtin_amdgcn_s_setprio(0);

    // ---- online softmax (exp2 domain; scale folded into Q) ----
    float mx[2];
#pragma unroll
    for (int qi = 0; qi < 2; ++qi) {
      float a0 = fmaxf(fmaxf(sacc[0][qi][0], sacc[0][qi][1]), fmaxf(sacc[0][qi][2], sacc[0][qi][3]));
      float a1 = fmaxf(fmaxf(sacc[1][qi][0], sacc[1][qi][1]), fmaxf(sacc[1][qi][2], sacc[1][qi][3]));
      float a2 = fmaxf(fmaxf(sacc[2][qi][0], sacc[2][qi][1]), fmaxf(sacc[2][qi][2], sacc[2][qi][3]));
      float a3 = fmaxf(fmaxf(sacc[3][qi][0], sacc[3][qi][1]), fmaxf(sacc[3][qi][2], sacc[3][qi][3]));
      float a = fmaxf(fmaxf(a0, a1), fmaxf(a2, a3));
      a = fmaxf(a, __shfl_xor(a, 16));
      a = fmaxf(a, __shfl_xor(a, 32));
      mx[qi] = a;
    }
    // defer-max: only rescale when a row's max grew past THR (log2 units)
    if (__any((mx[0] > mrun[0] + 10.f) || (mx[1] > mrun[1] + 10.f))) {
#pragma unroll
      for (int qi = 0; qi < 2; ++qi) {
        float mnew = fmaxf(mrun[qi], mx[qi]);
        float f = __builtin_amdgcn_exp2f(mrun[qi] - mnew);
        lrun[qi] *= f;
        mrun[qi] = mnew;
#pragma unroll
        for (int ei = 0; ei < 4; ++ei)
#pragma unroll
          for (int r = 0; r < 4; ++r) oacc[ei][qi][r] *= f;
      }
    }

    uint32_t pw[2][2][4];  // [qi][ks][word]
#pragma unroll
    for (int qi = 0; qi < 2; ++qi) {
      float p[4][4];
#pragma unroll
      for (int mi = 0; mi < 4; ++mi)
#pragma unroll
        for (int r = 0; r < 4; ++r)
          p[mi][r] = __builtin_amdgcn_exp2f(sacc[mi][qi][r] - mrun[qi]);
      float s0 = (p[0][0] + p[0][1]) + (p[0][2] + p[0][3]);
      float s1 = (p[1][0] + p[1][1]) + (p[1][2] + p[1][3]);
      float s2 = (p[2][0] + p[2][1]) + (p[2][2] + p[2][3]);
      float s3 = (p[3][0] + p[3][1]) + (p[3][2] + p[3][3]);
      float sum = (s0 + s1) + (s2 + s3);
      sum += __shfl_xor(sum, 16);
      sum += __shfl_xor(sum, 32);
      lrun[qi] += sum;
#pragma unroll
      for (int ks = 0; ks < 2; ++ks) {
        asm("v_cvt_pk_bf16_f32 %0, %1, %2" : "=v"(pw[qi][ks][0]) : "v"(p[ks * 2][0]), "v"(p[ks * 2][1]));
        asm("v_cvt_pk_bf16_f32 %0, %1, %2" : "=v"(pw[qi][ks][1]) : "v"(p[ks * 2][2]), "v"(p[ks * 2][3]));
        asm("v_cvt_pk_bf16_f32 %0, %1, %2" : "=v"(pw[qi][ks][2]) : "v"(p[ks * 2 + 1][0]), "v"(p[ks * 2 + 1][1]));
        asm("v_cvt_pk_bf16_f32 %0, %1, %2" : "=v"(pw[qi][ks][3]) : "v"(p[ks * 2 + 1][2]), "v"(p[ks * 2 + 1][3]));
      }
    }

    // ---- PV: att^T[e][q] += V^T-frag (k-permuted) * P-frag ----
    __builtin_amdgcn_s_setprio(1);
#pragma unroll
    for (int ks = 0; ks < 2; ++ks)
#pragma unroll
      for (int ei = 0; ei < 4; ++ei) {
        int row = ei * 16 + c;
        int blk0 = (ks * 4 + (g >> 1)) ^ (row & 7);
        short4v v0 = *(const short4v*)&Vs[buf][row * 64 + blk0 * 8 + (g & 1) * 4];
        int blk1 = (ks * 4 + 2 + (g >> 1)) ^ (row & 7);
        short4v v1 = *(const short4v*)&Vs[buf][row * 64 + blk1 * 8 + (g & 1) * 4];
        short8 vf = {v0[0], v0[1], v0[2], v0[3], v1[0], v1[1], v1[2], v1[3]};
#pragma unroll
        for (int qi = 0; qi < 2; ++qi) {
          union { uint32_t w[4]; short8 s; } pu;
          pu.w[0] = pw[qi][ks][0]; pu.w[1] = pw[qi][ks][1];
          pu.w[2] = pw[qi][ks][2]; pu.w[3] = pw[qi][ks][3];
          oacc[ei][qi] = __builtin_amdgcn_mfma_f32_16x16x32_bf16(vf, pu.s, oacc[ei][qi], 0, 0, 0);
        }
      }
    __builtin_amdgcn_s_setprio(0);

    __syncthreads();
  }

  // ---- epilogue ----
  int b = bh >> 4, h = bh & 15;
#pragma unroll
  for (int qi = 0; qi < 2; ++qi) {
    float inv = 1.0f / lrun[qi];
    int s = q0 + qi * 16 + c;
#pragma unroll
    for (int ei = 0; ei < 4; ++ei) {
      short4v o;
#pragma unroll
      for (int r = 0; r < 4; ++r) o[r] = bf16r(oacc[ei][qi][r] * inv);
      *(short4v*)&attb[(size_t)(b * 2048 + s) * 1024 + h * 64 + ei * 16 + g * 4] = o;
    }
  }
}

extern "C" void kernel_launch(void* const* d_in, const int* in_sizes, int n_in,
                              void* d_out, int out_size, void* d_ws, size_t ws_size,
                              hipStream_t stream) {
  const float* x  = (const float*)d_in[0];
  const float* wq = (const float*)d_in[1];
  const float* bq = (const float*)d_in[2];
  const float* wk = (const float*)d_in[3];
  const float* bk = (const float*)d_in[4];
  const float* wv = (const float*)d_in[5];
  const float* bv = (const float*)d_in[6];
  const float* wo = (const float*)d_in[7];
  const float* bo = (const float*)d_in[8];
  float* out = (float*)d_out;

  uint8_t* ws = (uint8_t*)d_ws;
  short* xb  = (short*)(ws);                  // 16 MB: x bf16 (reused as att after QKV GEMM)
  short* wt  = (short*)(ws + (16u << 20));    // 6 MB : Wt_qkv
  short* wob = (short*)(ws + (22u << 20));    // 2 MB : wo bf16
  short* qb  = (short*)(ws + (24u << 20));    // 16 MB: Q (scaled) [bh][s][64]
  short* kb  = (short*)(ws + (40u << 20));    // 16 MB: K [bh][s][64]
  short* vb  = (short*)(ws + (56u << 20));    // 16 MB: V [bh][s][64]
  short* vtb = (short*)(ws + (72u << 20));    // 16 MB: V^T [bh][64][2048]
  short* attb = xb;

  k_cvt<<<8192, 256, 0, stream>>>(x, xb, 2097152);
  k_cvt<<<1024, 256, 0, stream>>>(wo, wob, 262144);
  k_cvt_wt<<<dim3(16, 16, 3), 256, 0, stream>>>(wq, wk, wv, wt);
  k_gemm<0><<<dim3(24, 64), 256, 0, stream>>>(xb, wt, bq, bk, bv, qb, kb, vb, nullptr);
  k_vt<<<dim3(32, 64), 256, 0, stream>>>(vb, vtb);
  k_attn<<<dim3(16, 64), 256, 0, stream>>>(qb, kb, vtb, attb);
  k_gemm<1><<<dim3(8, 64), 256, 0, stream>>>(attb, wob, bo, nullptr, nullptr,
                                             nullptr, nullptr, nullptr, out);
}

// Round 3
// 210.648 us; speedup vs baseline: 1.1517x; 1.0823x over previous
//
#include <hip/hip_runtime.h>
#include <hip/hip_bf16.h>
#include <stdint.h>

typedef __attribute__((ext_vector_type(8))) short short8;
typedef __attribute__((ext_vector_type(4))) short short4v;
typedef __attribute__((ext_vector_type(4))) float f32x4;
typedef __attribute__((ext_vector_type(4))) float float4v;

#define LOG2E_OVER8 0.18033688011112042f  // (1/8)*log2(e), folded into Q

__device__ __forceinline__ short bf16r(float f) {  // f32 -> bf16 RNE
  union { float f; uint32_t u; } v; v.f = f;
  uint32_t r = (v.u + 0x7FFFu + ((v.u >> 16) & 1u)) >> 16;
  return (short)r;
}

__device__ __forceinline__ void gload16(const void* g, void* l) {
  __builtin_amdgcn_global_load_lds((const __attribute__((address_space(1))) void*)g,
                                   (__attribute__((address_space(3))) void*)l, 16, 0, 0);
}

// ---------------- elementwise f32 -> bf16 (x, wo) ----------------
__global__ void k_cvt(const float* __restrict__ in, short* __restrict__ out, int n4) {
  int i = blockIdx.x * 256 + threadIdx.x;
  if (i >= n4) return;
  float4v v = *(const float4v*)(in + (size_t)i * 4);
  short4v o = { bf16r(v[0]), bf16r(v[1]), bf16r(v[2]), bf16r(v[3]) };
  *(short4v*)(out + (size_t)i * 4) = o;
}

// ---------------- wq/wk/wv [16][1024][64] -> Wt [3072][1024] bf16 (B^T layout) ----------------
__global__ void k_cvt_wt(const float* __restrict__ wq, const float* __restrict__ wk,
                         const float* __restrict__ wv, short* __restrict__ wt) {
  __shared__ short tile[64][65];
  int kt = blockIdx.x, h = blockIdx.y, wsel = blockIdx.z;
  const float* src = wsel == 0 ? wq : (wsel == 1 ? wk : wv);
  int tid = threadIdx.x;
  {
    int e = tid & 63, r4 = tid >> 6;
#pragma unroll
    for (int p = 0; p < 16; ++p) {
      int kk = p * 4 + r4;
      tile[kk][e] = bf16r(src[h * 65536 + (kt * 64 + kk) * 64 + e]);
    }
  }
  __syncthreads();
  {
    int kk = tid & 63, r4 = tid >> 6;
#pragma unroll
    for (int p = 0; p < 16; ++p) {
      int e = p * 4 + r4;
      wt[(size_t)(wsel * 1024 + h * 64 + e) * 1024 + kt * 64 + kk] = tile[kk][e];
    }
  }
}

// ---------------- V [bh][s][64] -> Vt [bh][64][2048] bf16 ----------------
__global__ void k_vt(const short* __restrict__ vb, short* __restrict__ vt) {
  __shared__ short tile[64][65];
  int st = blockIdx.x, bh = blockIdx.y;
  int tid = threadIdx.x;
  {
    int e = tid & 63, r4 = tid >> 6;
#pragma unroll
    for (int p = 0; p < 16; ++p) {
      int ss = p * 4 + r4;
      tile[ss][e] = vb[(size_t)(bh * 2048 + st * 64 + ss) * 64 + e];
    }
  }
  __syncthreads();
  {
    int ss = tid & 63, r4 = tid >> 6;
#pragma unroll
    for (int p = 0; p < 16; ++p) {
      int e = p * 4 + r4;
      vt[(size_t)(bh * 64 + e) * 2048 + st * 64 + ss] = tile[ss][e];
    }
  }
}

// ---------------- GEMM: C[m][n] = sum_k A[m][k]*Bt[n][k], K=1024, tile 128x128, BK=32 ----------------
template<int EPI>
__global__ __launch_bounds__(256, 2) void k_gemm(
    const short* __restrict__ A, const short* __restrict__ Bt,
    const float* __restrict__ b0, const float* __restrict__ b1, const float* __restrict__ b2,
    short* __restrict__ qb, short* __restrict__ kb, short* __restrict__ vb,
    float* __restrict__ outp) {
  __shared__ short As[2][128 * 32];
  __shared__ short Bs[2][128 * 32];
  int tid = threadIdx.x;
  int l = tid & 63, w = tid >> 6;
  int g = l >> 4, c = l & 15;
  int wm = w >> 1, wn = w & 1;
  int m0 = blockIdx.y * 128, n0 = blockIdx.x * 128;

  f32x4 acc[4][4];
#pragma unroll
  for (int i = 0; i < 4; ++i)
#pragma unroll
    for (int j = 0; j < 4; ++j) acc[i][j] = (f32x4){0.f, 0.f, 0.f, 0.f};

  auto stage = [&](int buf, int kt) {
#pragma unroll
    for (int i = 0; i < 2; ++i) {
      int ch = w * 128 + i * 64 + l;
      int row = ch >> 2, cbs = ch & 3;
      int sb = cbs ^ ((row >> 1) & 3);
      gload16(A + (size_t)(m0 + row) * 1024 + kt * 32 + sb * 8,
              &As[buf][(w * 128 + i * 64) * 8]);
      gload16(Bt + (size_t)(n0 + row) * 1024 + kt * 32 + sb * 8,
              &Bs[buf][(w * 128 + i * 64) * 8]);
    }
  };

  stage(0, 0);
  __syncthreads();
  for (int kt = 0; kt < 32; ++kt) {
    int buf = kt & 1;
    if (kt + 1 < 32) stage(buf ^ 1, kt + 1);
    short8 af[4], bfr[4];
#pragma unroll
    for (int mi = 0; mi < 4; ++mi) {
      int row = wm * 64 + mi * 16 + c;
      int blk = g ^ ((row >> 1) & 3);
      af[mi] = *(const short8*)&As[buf][row * 32 + blk * 8];
    }
#pragma unroll
    for (int ni = 0; ni < 4; ++ni) {
      int row = wn * 64 + ni * 16 + c;
      int blk = g ^ ((row >> 1) & 3);
      bfr[ni] = *(const short8*)&Bs[buf][row * 32 + blk * 8];
    }
#pragma unroll
    for (int mi = 0; mi < 4; ++mi)
#pragma unroll
      for (int ni = 0; ni < 4; ++ni)
        acc[mi][ni] = __builtin_amdgcn_mfma_f32_16x16x32_bf16(af[mi], bfr[ni], acc[mi][ni], 0, 0, 0);
    __syncthreads();
  }

#pragma unroll
  for (int mi = 0; mi < 4; ++mi)
#pragma unroll
    for (int ni = 0; ni < 4; ++ni) {
      int n = n0 + wn * 64 + ni * 16 + c;
      if (EPI == 0) {
        int sel = n >> 10, nn = n & 1023;
        int h = nn >> 6, e = nn & 63;
        const float* bp = sel == 0 ? b0 : (sel == 1 ? b1 : b2);
        short* dst = sel == 0 ? qb : (sel == 1 ? kb : vb);
        float bias = bp[nn];
        float sc = (sel == 0) ? LOG2E_OVER8 : 1.0f;
#pragma unroll
        for (int r = 0; r < 4; ++r) {
          int m = m0 + wm * 64 + mi * 16 + g * 4 + r;
          int b = m >> 11, s = m & 2047;
          float v = (acc[mi][ni][r] + bias) * sc;
          dst[(size_t)((b * 16 + h) * 2048 + s) * 64 + e] = bf16r(v);
        }
      } else {
        float bias = b0[n];
#pragma unroll
        for (int r = 0; r < 4; ++r) {
          int m = m0 + wm * 64 + mi * 16 + g * 4 + r;
          outp[(size_t)m * 1024 + n] = acc[mi][ni][r] + bias;
        }
      }
    }
}

// ---------------- flash attention ----------------
// 4 waves x 64 Q-rows = 256-row Q tile; KV tile 64, double-buffered LDS.
// Swapped QK^T (S^T=mfma(K,Q)); steady-state tile has ZERO cross-lane ops:
// per-lane defer-max check + per-lane partial lrun (reduced once in epilogue).
__global__ __launch_bounds__(256, 2) void k_attn(
    const short* __restrict__ Qb, const short* __restrict__ Kb,
    const short* __restrict__ Vt, short* __restrict__ attb) {
  __shared__ short Ks[2][64 * 64];
  __shared__ short Vs[2][64 * 64];
  int tid = threadIdx.x;
  int l = tid & 63, w = tid >> 6;
  int g = l >> 4, c = l & 15;
  int qt = blockIdx.x, bh = blockIdx.y;
  int q0 = qt * 256 + w * 64;

  const short* Qh = Qb + (size_t)bh * 2048 * 64;
  short8 qf[4][2];
#pragma unroll
  for (int qi = 0; qi < 4; ++qi)
#pragma unroll
    for (int es = 0; es < 2; ++es)
      qf[qi][es] = *(const short8*)&Qh[(size_t)(q0 + qi * 16 + c) * 64 + es * 32 + g * 8];

  const f32x4 z4 = (f32x4){0.f, 0.f, 0.f, 0.f};
  f32x4 oacc[4][4];  // [ei][qi]
#pragma unroll
  for (int i = 0; i < 4; ++i)
#pragma unroll
    for (int j = 0; j < 4; ++j) oacc[i][j] = z4;
  float mrun[4] = {-3e38f, -3e38f, -3e38f, -3e38f};
  float lrun[4] = {0.f, 0.f, 0.f, 0.f};  // per-lane partial row sums

  auto stageKV = [&](int buf, int t0) {
#pragma unroll
    for (int i = 0; i < 2; ++i) {
      int ch = w * 128 + i * 64 + l;
      int row = ch >> 3, cbs = ch & 7;
      int sb = cbs ^ (row & 7);
      gload16(Kb + (size_t)(bh * 2048 + t0 + row) * 64 + sb * 8,
              &Ks[buf][(w * 128 + i * 64) * 8]);
      gload16(Vt + (size_t)(bh * 64 + row) * 2048 + t0 + sb * 8,
              &Vs[buf][(w * 128 + i * 64) * 8]);
    }
  };

  stageKV(0, 0);
  __syncthreads();

  for (int t = 0; t < 32; ++t) {
    int buf = t & 1;
    if (t + 1 < 32) stageKV(buf ^ 1, (t + 1) * 64);

    // ---- S^T = K * Q^T ----
    short8 kf0[4], kf1[4];
#pragma unroll
    for (int mi = 0; mi < 4; ++mi) {
      int row = mi * 16 + c;
      kf0[mi] = *(const short8*)&Ks[buf][row * 64 + (g ^ (row & 7)) * 8];
      kf1[mi] = *(const short8*)&Ks[buf][row * 64 + ((4 + g) ^ (row & 7)) * 8];
    }
    f32x4 sacc[4][4];  // [mi][qi]
    __builtin_amdgcn_s_setprio(1);
#pragma unroll
    for (int mi = 0; mi < 4; ++mi)
#pragma unroll
      for (int qi = 0; qi < 4; ++qi)
        sacc[mi][qi] = __builtin_amdgcn_mfma_f32_16x16x32_bf16(kf0[mi], qf[qi][0], z4, 0, 0, 0);
#pragma unroll
    for (int mi = 0; mi < 4; ++mi)
#pragma unroll
      for (int qi = 0; qi < 4; ++qi)
        sacc[mi][qi] = __builtin_amdgcn_mfma_f32_16x16x32_bf16(kf1[mi], qf[qi][1], sacc[mi][qi], 0, 0, 0);
    __builtin_amdgcn_s_setprio(0);

    // ---- per-lane max over this lane's 16 k-values of each row ----
    float mx[4];
#pragma unroll
    for (int qi = 0; qi < 4; ++qi) {
      float a0 = fmaxf(fmaxf(sacc[0][qi][0], sacc[0][qi][1]), fmaxf(sacc[0][qi][2], sacc[0][qi][3]));
      float a1 = fmaxf(fmaxf(sacc[1][qi][0], sacc[1][qi][1]), fmaxf(sacc[1][qi][2], sacc[1][qi][3]));
      float a2 = fmaxf(fmaxf(sacc[2][qi][0], sacc[2][qi][1]), fmaxf(sacc[2][qi][2], sacc[2][qi][3]));
      float a3 = fmaxf(fmaxf(sacc[3][qi][0], sacc[3][qi][1]), fmaxf(sacc[3][qi][2], sacc[3][qi][3]));
      mx[qi] = fmaxf(fmaxf(a0, a1), fmaxf(a2, a3));
    }
    // defer-max: rescale only when some lane's local max outgrows mrun by THR=8
    bool grow = (mx[0] > mrun[0] + 8.f) || (mx[1] > mrun[1] + 8.f) ||
                (mx[2] > mrun[2] + 8.f) || (mx[3] > mrun[3] + 8.f);
    if (__any(grow)) {
#pragma unroll
      for (int qi = 0; qi < 4; ++qi) {
        float a = mx[qi];
        a = fmaxf(a, __shfl_xor(a, 16));
        a = fmaxf(a, __shfl_xor(a, 32));
        float mnew = fmaxf(mrun[qi], a);
        float f = __builtin_amdgcn_exp2f(mrun[qi] - mnew);
        lrun[qi] *= f;
        mrun[qi] = mnew;
#pragma unroll
        for (int ei = 0; ei < 4; ++ei)
#pragma unroll
          for (int r = 0; r < 4; ++r) oacc[ei][qi][r] *= f;
      }
    }

    // ---- P = exp2(S - mrun), per-lane partial sums, pack to bf16 ----
    uint32_t pw[4][2][4];  // [qi][ks][word]
#pragma unroll
    for (int qi = 0; qi < 4; ++qi) {
      float p[4][4];
#pragma unroll
      for (int mi = 0; mi < 4; ++mi)
#pragma unroll
        for (int r = 0; r < 4; ++r)
          p[mi][r] = __builtin_amdgcn_exp2f(sacc[mi][qi][r] - mrun[qi]);
      float s0 = (p[0][0] + p[0][1]) + (p[0][2] + p[0][3]);
      float s1 = (p[1][0] + p[1][1]) + (p[1][2] + p[1][3]);
      float s2 = (p[2][0] + p[2][1]) + (p[2][2] + p[2][3]);
      float s3 = (p[3][0] + p[3][1]) + (p[3][2] + p[3][3]);
      lrun[qi] += (s0 + s1) + (s2 + s3);
#pragma unroll
      for (int ks = 0; ks < 2; ++ks) {
        asm("v_cvt_pk_bf16_f32 %0, %1, %2" : "=v"(pw[qi][ks][0]) : "v"(p[ks * 2][0]), "v"(p[ks * 2][1]));
        asm("v_cvt_pk_bf16_f32 %0, %1, %2" : "=v"(pw[qi][ks][1]) : "v"(p[ks * 2][2]), "v"(p[ks * 2][3]));
        asm("v_cvt_pk_bf16_f32 %0, %1, %2" : "=v"(pw[qi][ks][2]) : "v"(p[ks * 2 + 1][0]), "v"(p[ks * 2 + 1][1]));
        asm("v_cvt_pk_bf16_f32 %0, %1, %2" : "=v"(pw[qi][ks][3]) : "v"(p[ks * 2 + 1][2]), "v"(p[ks * 2 + 1][3]));
      }
    }

    // ---- PV: att^T[e][q] += V^T-frag (k-permuted) * P-frag ----
    __builtin_amdgcn_s_setprio(1);
#pragma unroll
    for (int ks = 0; ks < 2; ++ks)
#pragma unroll
      for (int ei = 0; ei < 4; ++ei) {
        int row = ei * 16 + c;
        int blk0 = (ks * 4 + (g >> 1)) ^ (row & 7);
        short4v v0 = *(const short4v*)&Vs[buf][row * 64 + blk0 * 8 + (g & 1) * 4];
        int blk1 = (ks * 4 + 2 + (g >> 1)) ^ (row & 7);
        short4v v1 = *(const short4v*)&Vs[buf][row * 64 + blk1 * 8 + (g & 1) * 4];
        short8 vf = {v0[0], v0[1], v0[2], v0[3], v1[0], v1[1], v1[2], v1[3]};
#pragma unroll
        for (int qi = 0; qi < 4; ++qi) {
          union { uint32_t w[4]; short8 s; } pu;
          pu.w[0] = pw[qi][ks][0]; pu.w[1] = pw[qi][ks][1];
          pu.w[2] = pw[qi][ks][2]; pu.w[3] = pw[qi][ks][3];
          oacc[ei][qi] = __builtin_amdgcn_mfma_f32_16x16x32_bf16(vf, pu.s, oacc[ei][qi], 0, 0, 0);
        }
      }
    __builtin_amdgcn_s_setprio(0);

    __syncthreads();
  }

  // ---- epilogue: reduce lrun across lanes once, normalize, store ----
  int b = bh >> 4, h = bh & 15;
#pragma unroll
  for (int qi = 0; qi < 4; ++qi) {
    float lt = lrun[qi];
    lt += __shfl_xor(lt, 16);
    lt += __shfl_xor(lt, 32);
    float inv = 1.0f / lt;
    int s = q0 + qi * 16 + c;
#pragma unroll
    for (int ei = 0; ei < 4; ++ei) {
      short4v o;
#pragma unroll
      for (int r = 0; r < 4; ++r) o[r] = bf16r(oacc[ei][qi][r] * inv);
      *(short4v*)&attb[(size_t)(b * 2048 + s) * 1024 + h * 64 + ei * 16 + g * 4] = o;
    }
  }
}

extern "C" void kernel_launch(void* const* d_in, const int* in_sizes, int n_in,
                              void* d_out, int out_size, void* d_ws, size_t ws_size,
                              hipStream_t stream) {
  const float* x  = (const float*)d_in[0];
  const float* wq = (const float*)d_in[1];
  const float* bq = (const float*)d_in[2];
  const float* wk = (const float*)d_in[3];
  const float* bk = (const float*)d_in[4];
  const float* wv = (const float*)d_in[5];
  const float* bv = (const float*)d_in[6];
  const float* wo = (const float*)d_in[7];
  const float* bo = (const float*)d_in[8];
  float* out = (float*)d_out;

  uint8_t* ws = (uint8_t*)d_ws;
  short* xb  = (short*)(ws);                  // 16 MB: x bf16 (reused as att after QKV GEMM)
  short* wt  = (short*)(ws + (16u << 20));    // 6 MB : Wt_qkv
  short* wob = (short*)(ws + (22u << 20));    // 2 MB : wo bf16
  short* qb  = (short*)(ws + (24u << 20));    // 16 MB: Q (scaled) [bh][s][64]
  short* kb  = (short*)(ws + (40u << 20));    // 16 MB: K [bh][s][64]
  short* vb  = (short*)(ws + (56u << 20));    // 16 MB: V [bh][s][64]
  short* vtb = (short*)(ws + (72u << 20));    // 16 MB: V^T [bh][64][2048]
  short* attb = xb;

  k_cvt<<<8192, 256, 0, stream>>>(x, xb, 2097152);
  k_cvt<<<1024, 256, 0, stream>>>(wo, wob, 262144);
  k_cvt_wt<<<dim3(16, 16, 3), 256, 0, stream>>>(wq, wk, wv, wt);
  k_gemm<0><<<dim3(24, 64), 256, 0, stream>>>(xb, wt, bq, bk, bv, qb, kb, vb, nullptr);
  k_vt<<<dim3(32, 64), 256, 0, stream>>>(vb, vtb);
  k_attn<<<dim3(8, 64), 256, 0, stream>>>(qb, kb, vtb, attb);
  k_gemm<1><<<dim3(8, 64), 256, 0, stream>>>(attb, wob, bo, nullptr, nullptr,
                                             nullptr, nullptr, nullptr, out);
}

// Round 4
// 209.309 us; speedup vs baseline: 1.1590x; 1.0064x over previous
//
#include <hip/hip_runtime.h>
#include <hip/hip_bf16.h>
#include <stdint.h>

typedef __attribute__((ext_vector_type(8))) short short8;
typedef __attribute__((ext_vector_type(4))) short short4v;
typedef __attribute__((ext_vector_type(4))) float f32x4;
typedef __attribute__((ext_vector_type(4))) float float4v;

#define LOG2E_OVER8 0.18033688011112042f  // (1/8)*log2(e), folded into Q

__device__ __forceinline__ short bf16r(float f) {  // f32 -> bf16 RNE
  union { float f; uint32_t u; } v; v.f = f;
  uint32_t r = (v.u + 0x7FFFu + ((v.u >> 16) & 1u)) >> 16;
  return (short)r;
}

__device__ __forceinline__ void gload16(const void* g, void* l) {
  __builtin_amdgcn_global_load_lds((const __attribute__((address_space(1))) void*)g,
                                   (__attribute__((address_space(3))) void*)l, 16, 0, 0);
}

// ---------------- elementwise f32 -> bf16 (x, wo) ----------------
__global__ void k_cvt(const float* __restrict__ in, short* __restrict__ out, int n4) {
  int i = blockIdx.x * 256 + threadIdx.x;
  if (i >= n4) return;
  float4v v = *(const float4v*)(in + (size_t)i * 4);
  short4v o = { bf16r(v[0]), bf16r(v[1]), bf16r(v[2]), bf16r(v[3]) };
  *(short4v*)(out + (size_t)i * 4) = o;
}

// ---------------- wq/wk/wv [16][1024][64] -> Wt [3072][1024] bf16 (B^T layout) ----------------
__global__ void k_cvt_wt(const float* __restrict__ wq, const float* __restrict__ wk,
                         const float* __restrict__ wv, short* __restrict__ wt) {
  __shared__ short tile[64][65];
  int kt = blockIdx.x, h = blockIdx.y, wsel = blockIdx.z;
  const float* src = wsel == 0 ? wq : (wsel == 1 ? wk : wv);
  int tid = threadIdx.x;
  {
    int e = tid & 63, r4 = tid >> 6;
#pragma unroll
    for (int p = 0; p < 16; ++p) {
      int kk = p * 4 + r4;
      tile[kk][e] = bf16r(src[h * 65536 + (kt * 64 + kk) * 64 + e]);
    }
  }
  __syncthreads();
  {
    int kk = tid & 63, r4 = tid >> 6;
#pragma unroll
    for (int p = 0; p < 16; ++p) {
      int e = p * 4 + r4;
      wt[(size_t)(wsel * 1024 + h * 64 + e) * 1024 + kt * 64 + kk] = tile[kk][e];
    }
  }
}

// ---------------- V [bh][s][64] -> Vt [bh][64][2048] bf16 ----------------
__global__ void k_vt(const short* __restrict__ vb, short* __restrict__ vt) {
  __shared__ short tile[64][65];
  int st = blockIdx.x, bh = blockIdx.y;
  int tid = threadIdx.x;
  {
    int e = tid & 63, r4 = tid >> 6;
#pragma unroll
    for (int p = 0; p < 16; ++p) {
      int ss = p * 4 + r4;
      tile[ss][e] = vb[(size_t)(bh * 2048 + st * 64 + ss) * 64 + e];
    }
  }
  __syncthreads();
  {
    int ss = tid & 63, r4 = tid >> 6;
#pragma unroll
    for (int p = 0; p < 16; ++p) {
      int e = p * 4 + r4;
      vt[(size_t)(bh * 64 + e) * 2048 + st * 64 + ss] = tile[ss][e];
    }
  }
}

// ---------------- GEMM: C[m][n] = sum_k A[m][k]*Bt[n][k], K=1024, tile 128x128, BK=32 ----------------
template<int EPI>
__global__ __launch_bounds__(256, 2) void k_gemm(
    const short* __restrict__ A, const short* __restrict__ Bt,
    const float* __restrict__ b0, const float* __restrict__ b1, const float* __restrict__ b2,
    short* __restrict__ qb, short* __restrict__ kb, short* __restrict__ vb,
    float* __restrict__ outp) {
  __shared__ short As[2][128 * 32];
  __shared__ short Bs[2][128 * 32];
  int tid = threadIdx.x;
  int l = tid & 63, w = tid >> 6;
  int g = l >> 4, c = l & 15;
  int wm = w >> 1, wn = w & 1;
  // XCD-chunked bijective blockIdx swizzle (nwg % 8 == 0): contiguous m-bands per XCD
  const int NBX = (EPI == 0) ? 24 : 8;
  const int nwg = NBX * 64;
  int orig = blockIdx.x + blockIdx.y * NBX;
  int swz = (orig & 7) * (nwg >> 3) + (orig >> 3);
  int m0 = (swz / NBX) * 128, n0 = (swz % NBX) * 128;

  f32x4 acc[4][4];
#pragma unroll
  for (int i = 0; i < 4; ++i)
#pragma unroll
    for (int j = 0; j < 4; ++j) acc[i][j] = (f32x4){0.f, 0.f, 0.f, 0.f};

  auto stage = [&](int buf, int kt) {
#pragma unroll
    for (int i = 0; i < 2; ++i) {
      int ch = w * 128 + i * 64 + l;
      int row = ch >> 2, cbs = ch & 3;
      int sb = cbs ^ ((row >> 1) & 3);
      gload16(A + (size_t)(m0 + row) * 1024 + kt * 32 + sb * 8,
              &As[buf][(w * 128 + i * 64) * 8]);
      gload16(Bt + (size_t)(n0 + row) * 1024 + kt * 32 + sb * 8,
              &Bs[buf][(w * 128 + i * 64) * 8]);
    }
  };

  stage(0, 0);
  __syncthreads();
  for (int kt = 0; kt < 32; ++kt) {
    int buf = kt & 1;
    if (kt + 1 < 32) stage(buf ^ 1, kt + 1);
    short8 af[4], bfr[4];
#pragma unroll
    for (int mi = 0; mi < 4; ++mi) {
      int row = wm * 64 + mi * 16 + c;
      int blk = g ^ ((row >> 1) & 3);
      af[mi] = *(const short8*)&As[buf][row * 32 + blk * 8];
    }
#pragma unroll
    for (int ni = 0; ni < 4; ++ni) {
      int row = wn * 64 + ni * 16 + c;
      int blk = g ^ ((row >> 1) & 3);
      bfr[ni] = *(const short8*)&Bs[buf][row * 32 + blk * 8];
    }
#pragma unroll
    for (int mi = 0; mi < 4; ++mi)
#pragma unroll
      for (int ni = 0; ni < 4; ++ni)
        acc[mi][ni] = __builtin_amdgcn_mfma_f32_16x16x32_bf16(af[mi], bfr[ni], acc[mi][ni], 0, 0, 0);
    __syncthreads();
  }

#pragma unroll
  for (int mi = 0; mi < 4; ++mi)
#pragma unroll
    for (int ni = 0; ni < 4; ++ni) {
      int n = n0 + wn * 64 + ni * 16 + c;
      if (EPI == 0) {
        int sel = n >> 10, nn = n & 1023;
        int h = nn >> 6, e = nn & 63;
        const float* bp = sel == 0 ? b0 : (sel == 1 ? b1 : b2);
        short* dst = sel == 0 ? qb : (sel == 1 ? kb : vb);
        float bias = bp[nn];
        float sc = (sel == 0) ? LOG2E_OVER8 : 1.0f;
#pragma unroll
        for (int r = 0; r < 4; ++r) {
          int m = m0 + wm * 64 + mi * 16 + g * 4 + r;
          int b = m >> 11, s = m & 2047;
          float v = (acc[mi][ni][r] + bias) * sc;
          dst[(size_t)((b * 16 + h) * 2048 + s) * 64 + e] = bf16r(v);
        }
      } else {
        float bias = b0[n];
#pragma unroll
        for (int r = 0; r < 4; ++r) {
          int m = m0 + wm * 64 + mi * 16 + g * 4 + r;
          outp[(size_t)m * 1024 + n] = acc[mi][ni][r] + bias;
        }
      }
    }
}

// ---------------- flash attention ----------------
// 2 waves x 64 Q-rows = 128-row Q tile; grid 16x64 = 1024 blocks = 4 independent
// barrier domains per CU. KV tile 64, double-buffered LDS. Swapped QK^T.
// All swizzled LDS offsets hoisted; P-fragments built once per (qi,ks).
__global__ __launch_bounds__(128, 2) void k_attn(
    const short* __restrict__ Qb, const short* __restrict__ Kb,
    const short* __restrict__ Vt, short* __restrict__ attb) {
  __shared__ short Ks[2][64 * 64];
  __shared__ short Vs[2][64 * 64];
  int tid = threadIdx.x;
  int l = tid & 63, w = tid >> 6;  // w in {0,1}
  int g = l >> 4, c = l & 15;
  // XCD-chunked swizzle: 8 consecutive heads per XCD (K+V working set 4MB = L2)
  int orig = blockIdx.x + blockIdx.y * 16;           // grid (16,64) -> 1024
  int swz = (orig & 7) * 128 + (orig >> 3);
  int qt = swz & 15, bh = swz >> 4;
  int q0 = qt * 128 + w * 64;

  const short* Qh = Qb + (size_t)bh * 2048 * 64;
  short8 qf[4][2];
#pragma unroll
  for (int qi = 0; qi < 4; ++qi)
#pragma unroll
    for (int es = 0; es < 2; ++es)
      qf[qi][es] = *(const short8*)&Qh[(size_t)(q0 + qi * 16 + c) * 64 + es * 32 + g * 8];

  // hoisted swizzled LDS element-offsets (loop-invariant)
  int koff[4][2];
#pragma unroll
  for (int mi = 0; mi < 4; ++mi) {
    int row = mi * 16 + c;
    koff[mi][0] = row * 64 + ((g ^ (row & 7)) * 8);
    koff[mi][1] = row * 64 + (((4 + g) ^ (row & 7)) * 8);
  }
  int voff[2][4][2];
#pragma unroll
  for (int ks = 0; ks < 2; ++ks)
#pragma unroll
    for (int ei = 0; ei < 4; ++ei) {
      int row = ei * 16 + c;
      voff[ks][ei][0] = row * 64 + (((ks * 4 + (g >> 1)) ^ (row & 7)) * 8) + (g & 1) * 4;
      voff[ks][ei][1] = row * 64 + (((ks * 4 + 2 + (g >> 1)) ^ (row & 7)) * 8) + (g & 1) * 4;
    }

  const f32x4 z4 = (f32x4){0.f, 0.f, 0.f, 0.f};
  f32x4 oacc[4][4];  // [ei][qi]
#pragma unroll
  for (int i = 0; i < 4; ++i)
#pragma unroll
    for (int j = 0; j < 4; ++j) oacc[i][j] = z4;
  float mrun[4] = {-3e38f, -3e38f, -3e38f, -3e38f};
  float lrun[4] = {0.f, 0.f, 0.f, 0.f};  // per-lane partial row sums

  auto stageKV = [&](int buf, int t0) {
#pragma unroll
    for (int i = 0; i < 4; ++i) {
      int ch = w * 256 + i * 64 + l;
      int row = ch >> 3, cbs = ch & 7;
      int sb = cbs ^ (row & 7);
      gload16(Kb + (size_t)(bh * 2048 + t0 + row) * 64 + sb * 8,
              &Ks[buf][(w * 256 + i * 64) * 8]);
      gload16(Vt + (size_t)(bh * 64 + row) * 2048 + t0 + sb * 8,
              &Vs[buf][(w * 256 + i * 64) * 8]);
    }
  };

  stageKV(0, 0);
  __syncthreads();

  for (int t = 0; t < 32; ++t) {
    int buf = t & 1;
    if (t + 1 < 32) stageKV(buf ^ 1, (t + 1) * 64);

    // ---- S^T = K * Q^T ----
    const short* Kbuf = &Ks[buf][0];
    short8 kf0[4], kf1[4];
#pragma unroll
    for (int mi = 0; mi < 4; ++mi) {
      kf0[mi] = *(const short8*)&Kbuf[koff[mi][0]];
      kf1[mi] = *(const short8*)&Kbuf[koff[mi][1]];
    }
    f32x4 sacc[4][4];  // [mi][qi]
    __builtin_amdgcn_s_setprio(1);
#pragma unroll
    for (int mi = 0; mi < 4; ++mi)
#pragma unroll
      for (int qi = 0; qi < 4; ++qi)
        sacc[mi][qi] = __builtin_amdgcn_mfma_f32_16x16x32_bf16(kf0[mi], qf[qi][0], z4, 0, 0, 0);
#pragma unroll
    for (int mi = 0; mi < 4; ++mi)
#pragma unroll
      for (int qi = 0; qi < 4; ++qi)
        sacc[mi][qi] = __builtin_amdgcn_mfma_f32_16x16x32_bf16(kf1[mi], qf[qi][1], sacc[mi][qi], 0, 0, 0);
    __builtin_amdgcn_s_setprio(0);

    // ---- per-lane max over this lane's 16 k-values of each row ----
    float mx[4];
#pragma unroll
    for (int qi = 0; qi < 4; ++qi) {
      float a0 = fmaxf(fmaxf(sacc[0][qi][0], sacc[0][qi][1]), fmaxf(sacc[0][qi][2], sacc[0][qi][3]));
      float a1 = fmaxf(fmaxf(sacc[1][qi][0], sacc[1][qi][1]), fmaxf(sacc[1][qi][2], sacc[1][qi][3]));
      float a2 = fmaxf(fmaxf(sacc[2][qi][0], sacc[2][qi][1]), fmaxf(sacc[2][qi][2], sacc[2][qi][3]));
      float a3 = fmaxf(fmaxf(sacc[3][qi][0], sacc[3][qi][1]), fmaxf(sacc[3][qi][2], sacc[3][qi][3]));
      mx[qi] = fmaxf(fmaxf(a0, a1), fmaxf(a2, a3));
    }
    // defer-max: rescale only when some lane's local max outgrows mrun by THR=8
    bool grow = (mx[0] > mrun[0] + 8.f) || (mx[1] > mrun[1] + 8.f) ||
                (mx[2] > mrun[2] + 8.f) || (mx[3] > mrun[3] + 8.f);
    if (__any(grow)) {
#pragma unroll
      for (int qi = 0; qi < 4; ++qi) {
        float a = mx[qi];
        a = fmaxf(a, __shfl_xor(a, 16));
        a = fmaxf(a, __shfl_xor(a, 32));
        float mnew = fmaxf(mrun[qi], a);
        float f = __builtin_amdgcn_exp2f(mrun[qi] - mnew);
        lrun[qi] *= f;
        mrun[qi] = mnew;
#pragma unroll
        for (int ei = 0; ei < 4; ++ei)
#pragma unroll
          for (int r = 0; r < 4; ++r) oacc[ei][qi][r] *= f;
      }
    }

    // ---- P = exp2(S - mrun), per-lane partial sums, pack to bf16 once ----
    short8 pf[4][2];  // [qi][ks]
#pragma unroll
    for (int qi = 0; qi < 4; ++qi) {
      float p[4][4];
#pragma unroll
      for (int mi = 0; mi < 4; ++mi)
#pragma unroll
        for (int r = 0; r < 4; ++r)
          p[mi][r] = __builtin_amdgcn_exp2f(sacc[mi][qi][r] - mrun[qi]);
      float s0 = (p[0][0] + p[0][1]) + (p[0][2] + p[0][3]);
      float s1 = (p[1][0] + p[1][1]) + (p[1][2] + p[1][3]);
      float s2 = (p[2][0] + p[2][1]) + (p[2][2] + p[2][3]);
      float s3 = (p[3][0] + p[3][1]) + (p[3][2] + p[3][3]);
      lrun[qi] += (s0 + s1) + (s2 + s3);
#pragma unroll
      for (int ks = 0; ks < 2; ++ks) {
        union { uint32_t w[4]; short8 s; } pu;
        asm("v_cvt_pk_bf16_f32 %0, %1, %2" : "=v"(pu.w[0]) : "v"(p[ks * 2][0]), "v"(p[ks * 2][1]));
        asm("v_cvt_pk_bf16_f32 %0, %1, %2" : "=v"(pu.w[1]) : "v"(p[ks * 2][2]), "v"(p[ks * 2][3]));
        asm("v_cvt_pk_bf16_f32 %0, %1, %2" : "=v"(pu.w[2]) : "v"(p[ks * 2 + 1][0]), "v"(p[ks * 2 + 1][1]));
        asm("v_cvt_pk_bf16_f32 %0, %1, %2" : "=v"(pu.w[3]) : "v"(p[ks * 2 + 1][2]), "v"(p[ks * 2 + 1][3]));
        pf[qi][ks] = pu.s;
      }
    }

    // ---- PV: att^T[e][q] += V^T-frag (k-permuted) * P-frag ----
    const short* Vbuf = &Vs[buf][0];
    __builtin_amdgcn_s_setprio(1);
#pragma unroll
    for (int ks = 0; ks < 2; ++ks)
#pragma unroll
      for (int ei = 0; ei < 4; ++ei) {
        short4v v0 = *(const short4v*)&Vbuf[voff[ks][ei][0]];
        short4v v1 = *(const short4v*)&Vbuf[voff[ks][ei][1]];
        short8 vf = {v0[0], v0[1], v0[2], v0[3], v1[0], v1[1], v1[2], v1[3]};
#pragma unroll
        for (int qi = 0; qi < 4; ++qi)
          oacc[ei][qi] = __builtin_amdgcn_mfma_f32_16x16x32_bf16(vf, pf[qi][ks], oacc[ei][qi], 0, 0, 0);
      }
    __builtin_amdgcn_s_setprio(0);

    __syncthreads();
  }

  // ---- epilogue: reduce lrun across lanes once, normalize, store ----
  int b = bh >> 4, h = bh & 15;
#pragma unroll
  for (int qi = 0; qi < 4; ++qi) {
    float lt = lrun[qi];
    lt += __shfl_xor(lt, 16);
    lt += __shfl_xor(lt, 32);
    float inv = 1.0f / lt;
    int s = q0 + qi * 16 + c;
#pragma unroll
    for (int ei = 0; ei < 4; ++ei) {
      short4v o;
#pragma unroll
      for (int r = 0; r < 4; ++r) o[r] = bf16r(oacc[ei][qi][r] * inv);
      *(short4v*)&attb[(size_t)(b * 2048 + s) * 1024 + h * 64 + ei * 16 + g * 4] = o;
    }
  }
}

extern "C" void kernel_launch(void* const* d_in, const int* in_sizes, int n_in,
                              void* d_out, int out_size, void* d_ws, size_t ws_size,
                              hipStream_t stream) {
  const float* x  = (const float*)d_in[0];
  const float* wq = (const float*)d_in[1];
  const float* bq = (const float*)d_in[2];
  const float* wk = (const float*)d_in[3];
  const float* bk = (const float*)d_in[4];
  const float* wv = (const float*)d_in[5];
  const float* bv = (const float*)d_in[6];
  const float* wo = (const float*)d_in[7];
  const float* bo = (const float*)d_in[8];
  float* out = (float*)d_out;

  uint8_t* ws = (uint8_t*)d_ws;
  short* xb  = (short*)(ws);                  // 16 MB: x bf16 (reused as att after QKV GEMM)
  short* wt  = (short*)(ws + (16u << 20));    // 6 MB : Wt_qkv
  short* wob = (short*)(ws + (22u << 20));    // 2 MB : wo bf16
  short* qb  = (short*)(ws + (24u << 20));    // 16 MB: Q (scaled) [bh][s][64]
  short* kb  = (short*)(ws + (40u << 20));    // 16 MB: K [bh][s][64]
  short* vb  = (short*)(ws + (56u << 20));    // 16 MB: V [bh][s][64]
  short* vtb = (short*)(ws + (72u << 20));    // 16 MB: V^T [bh][64][2048]
  short* attb = xb;

  k_cvt<<<8192, 256, 0, stream>>>(x, xb, 2097152);
  k_cvt<<<1024, 256, 0, stream>>>(wo, wob, 262144);
  k_cvt_wt<<<dim3(16, 16, 3), 256, 0, stream>>>(wq, wk, wv, wt);
  k_gemm<0><<<dim3(24, 64), 256, 0, stream>>>(xb, wt, bq, bk, bv, qb, kb, vb, nullptr);
  k_vt<<<dim3(32, 64), 256, 0, stream>>>(vb, vtb);
  k_attn<<<dim3(16, 64), 128, 0, stream>>>(qb, kb, vtb, attb);
  k_gemm<1><<<dim3(8, 64), 256, 0, stream>>>(attb, wob, bo, nullptr, nullptr,
                                             nullptr, nullptr, nullptr, out);
}

// Round 6
// 209.212 us; speedup vs baseline: 1.1596x; 1.0005x over previous
//
#include <hip/hip_runtime.h>
#include <hip/hip_bf16.h>
#include <stdint.h>

typedef __attribute__((ext_vector_type(8))) short short8;
typedef __attribute__((ext_vector_type(4))) short short4v;
typedef __attribute__((ext_vector_type(4))) float f32x4;
typedef __attribute__((ext_vector_type(4))) float float4v;

#define LOG2E_OVER8 0.18033688011112042f  // (1/8)*log2(e), folded into Q

__device__ __forceinline__ short bf16r(float f) {  // f32 -> bf16 RNE
  union { float f; uint32_t u; } v; v.f = f;
  uint32_t r = (v.u + 0x7FFFu + ((v.u >> 16) & 1u)) >> 16;
  return (short)r;
}

__device__ __forceinline__ void gload16(const void* g, void* l) {
  __builtin_amdgcn_global_load_lds((const __attribute__((address_space(1))) void*)g,
                                   (__attribute__((address_space(3))) void*)l, 16, 0, 0);
}

__device__ __forceinline__ float max3f(float a, float b, float c) {
  return fmaxf(fmaxf(a, b), c);  // fuses to v_max3_f32
}

// ---------------- elementwise f32 -> bf16 (x, wo) ----------------
__global__ void k_cvt(const float* __restrict__ in, short* __restrict__ out, int n4) {
  int i = blockIdx.x * 256 + threadIdx.x;
  if (i >= n4) return;
  float4v v = *(const float4v*)(in + (size_t)i * 4);
  short4v o = { bf16r(v[0]), bf16r(v[1]), bf16r(v[2]), bf16r(v[3]) };
  *(short4v*)(out + (size_t)i * 4) = o;
}

// ---------------- wq/wk/wv [16][1024][64] -> Wt [3072][1024] bf16 (B^T layout) ----------------
__global__ void k_cvt_wt(const float* __restrict__ wq, const float* __restrict__ wk,
                         const float* __restrict__ wv, short* __restrict__ wt) {
  __shared__ short tile[64][65];
  int kt = blockIdx.x, h = blockIdx.y, wsel = blockIdx.z;
  const float* src = wsel == 0 ? wq : (wsel == 1 ? wk : wv);
  int tid = threadIdx.x;
  {
    int e = tid & 63, r4 = tid >> 6;
#pragma unroll
    for (int p = 0; p < 16; ++p) {
      int kk = p * 4 + r4;
      tile[kk][e] = bf16r(src[h * 65536 + (kt * 64 + kk) * 64 + e]);
    }
  }
  __syncthreads();
  {
    int kk = tid & 63, r4 = tid >> 6;
#pragma unroll
    for (int p = 0; p < 16; ++p) {
      int e = p * 4 + r4;
      wt[(size_t)(wsel * 1024 + h * 64 + e) * 1024 + kt * 64 + kk] = tile[kk][e];
    }
  }
}

// ---------------- V [bh][s][64] -> Vt [bh][64][2048] bf16 ----------------
__global__ void k_vt(const short* __restrict__ vb, short* __restrict__ vt) {
  __shared__ short tile[64][65];
  int st = blockIdx.x, bh = blockIdx.y;
  int tid = threadIdx.x;
  {
    int e = tid & 63, r4 = tid >> 6;
#pragma unroll
    for (int p = 0; p < 16; ++p) {
      int ss = p * 4 + r4;
      tile[ss][e] = vb[(size_t)(bh * 2048 + st * 64 + ss) * 64 + e];
    }
  }
  __syncthreads();
  {
    int ss = tid & 63, r4 = tid >> 6;
#pragma unroll
    for (int p = 0; p < 16; ++p) {
      int e = p * 4 + r4;
      vt[(size_t)(bh * 64 + e) * 2048 + st * 64 + ss] = tile[ss][e];
    }
  }
}

// ---------------- GEMM: C[m][n] = sum_k A[m][k]*Bt[n][k], K=1024, tile 128x128, BK=32 ----------------
template<int EPI>
__global__ __launch_bounds__(256, 2) void k_gemm(
    const short* __restrict__ A, const short* __restrict__ Bt,
    const float* __restrict__ b0, const float* __restrict__ b1, const float* __restrict__ b2,
    short* __restrict__ qb, short* __restrict__ kb, short* __restrict__ vb,
    float* __restrict__ outp) {
  __shared__ short As[2][128 * 32];
  __shared__ short Bs[2][128 * 32];
  int tid = threadIdx.x;
  int l = tid & 63, w = tid >> 6;
  int g = l >> 4, c = l & 15;
  int wm = w >> 1, wn = w & 1;
  // XCD-chunked bijective blockIdx swizzle (nwg % 8 == 0): contiguous m-bands per XCD
  const int NBX = (EPI == 0) ? 24 : 8;
  const int nwg = NBX * 64;
  int orig = blockIdx.x + blockIdx.y * NBX;
  int swz = (orig & 7) * (nwg >> 3) + (orig >> 3);
  int m0 = (swz / NBX) * 128, n0 = (swz % NBX) * 128;

  f32x4 acc[4][4];
#pragma unroll
  for (int i = 0; i < 4; ++i)
#pragma unroll
    for (int j = 0; j < 4; ++j) acc[i][j] = (f32x4){0.f, 0.f, 0.f, 0.f};

  auto stage = [&](int buf, int kt) {
#pragma unroll
    for (int i = 0; i < 2; ++i) {
      int ch = w * 128 + i * 64 + l;
      int row = ch >> 2, cbs = ch & 3;
      int sb = cbs ^ ((row >> 1) & 3);
      gload16(A + (size_t)(m0 + row) * 1024 + kt * 32 + sb * 8,
              &As[buf][(w * 128 + i * 64) * 8]);
      gload16(Bt + (size_t)(n0 + row) * 1024 + kt * 32 + sb * 8,
              &Bs[buf][(w * 128 + i * 64) * 8]);
    }
  };

  stage(0, 0);
  __syncthreads();
  for (int kt = 0; kt < 32; ++kt) {
    int buf = kt & 1;
    if (kt + 1 < 32) stage(buf ^ 1, kt + 1);
    short8 af[4], bfr[4];
#pragma unroll
    for (int mi = 0; mi < 4; ++mi) {
      int row = wm * 64 + mi * 16 + c;
      int blk = g ^ ((row >> 1) & 3);
      af[mi] = *(const short8*)&As[buf][row * 32 + blk * 8];
    }
#pragma unroll
    for (int ni = 0; ni < 4; ++ni) {
      int row = wn * 64 + ni * 16 + c;
      int blk = g ^ ((row >> 1) & 3);
      bfr[ni] = *(const short8*)&Bs[buf][row * 32 + blk * 8];
    }
#pragma unroll
    for (int mi = 0; mi < 4; ++mi)
#pragma unroll
      for (int ni = 0; ni < 4; ++ni)
        acc[mi][ni] = __builtin_amdgcn_mfma_f32_16x16x32_bf16(af[mi], bfr[ni], acc[mi][ni], 0, 0, 0);
    __syncthreads();
  }

#pragma unroll
  for (int mi = 0; mi < 4; ++mi)
#pragma unroll
    for (int ni = 0; ni < 4; ++ni) {
      int n = n0 + wn * 64 + ni * 16 + c;
      if (EPI == 0) {
        int sel = n >> 10, nn = n & 1023;
        int h = nn >> 6, e = nn & 63;
        const float* bp = sel == 0 ? b0 : (sel == 1 ? b1 : b2);
        short* dst = sel == 0 ? qb : (sel == 1 ? kb : vb);
        float bias = bp[nn];
        float sc = (sel == 0) ? LOG2E_OVER8 : 1.0f;
#pragma unroll
        for (int r = 0; r < 4; ++r) {
          int m = m0 + wm * 64 + mi * 16 + g * 4 + r;
          int b = m >> 11, s = m & 2047;
          float v = (acc[mi][ni][r] + bias) * sc;
          dst[(size_t)((b * 16 + h) * 2048 + s) * 64 + e] = bf16r(v);
        }
      } else {
        float bias = b0[n];
#pragma unroll
        for (int r = 0; r < 4; ++r) {
          int m = m0 + wm * 64 + mi * 16 + g * 4 + r;
          outp[(size_t)m * 1024 + n] = acc[mi][ni][r] + bias;
        }
      }
    }
}

// ---------------- flash attention ----------------
// BISECT round: round-4-proven body (explicit koff/voff, per-lane lrun + epilogue
// shuffle reduce), ONLY geometry changed: 4 waves x 32 Q-rows = 128-row Q tile,
// grid 16x64 = 1024 blocks -> 4 blocks/CU = 16 waves/CU = 4 waves/SIMD.
__global__ __launch_bounds__(256, 4) void k_attn(
    const short* __restrict__ Qb, const short* __restrict__ Kb,
    const short* __restrict__ Vt, short* __restrict__ attb) {
  __shared__ short Ks[2][64 * 64];
  __shared__ short Vs[2][64 * 64];
  int tid = threadIdx.x;
  int l = tid & 63, w = tid >> 6;  // 4 waves
  int g = l >> 4, c = l & 15;
  // XCD-chunked swizzle: 8 consecutive heads per XCD (K+V working set L2-resident)
  int orig = blockIdx.x + blockIdx.y * 16;  // grid (16,64) -> 1024
  int swz = (orig & 7) * 128 + (orig >> 3);
  int qt = swz & 15, bh = swz >> 4;
  int q0 = qt * 128 + w * 32;

  const short* Qh = Qb + (size_t)bh * 2048 * 64;
  short8 qf[2][2];
#pragma unroll
  for (int qi = 0; qi < 2; ++qi)
#pragma unroll
    for (int es = 0; es < 2; ++es)
      qf[qi][es] = *(const short8*)&Qh[(size_t)(q0 + qi * 16 + c) * 64 + es * 32 + g * 8];

  // hoisted swizzled LDS element-offsets (round-4-proven formulas)
  int koff[4][2];
#pragma unroll
  for (int mi = 0; mi < 4; ++mi) {
    int row = mi * 16 + c;
    koff[mi][0] = row * 64 + ((g ^ (row & 7)) * 8);
    koff[mi][1] = row * 64 + (((4 + g) ^ (row & 7)) * 8);
  }
  int voff[2][4][2];
#pragma unroll
  for (int ks = 0; ks < 2; ++ks)
#pragma unroll
    for (int ei = 0; ei < 4; ++ei) {
      int row = ei * 16 + c;
      voff[ks][ei][0] = row * 64 + (((ks * 4 + (g >> 1)) ^ (row & 7)) * 8) + (g & 1) * 4;
      voff[ks][ei][1] = row * 64 + (((ks * 4 + 2 + (g >> 1)) ^ (row & 7)) * 8) + (g & 1) * 4;
    }

  const f32x4 z4 = (f32x4){0.f, 0.f, 0.f, 0.f};
  f32x4 oacc[4][2];  // [ei][qi]
#pragma unroll
  for (int i = 0; i < 4; ++i) { oacc[i][0] = z4; oacc[i][1] = z4; }
  float mrun[2] = {-3e38f, -3e38f};
  float lrun[2] = {0.f, 0.f};  // per-lane partial row sums

  auto stageKV = [&](int buf, int t0) {
#pragma unroll
    for (int i = 0; i < 2; ++i) {
      int ch = w * 128 + i * 64 + l;  // 0..511
      int row = ch >> 3, cbs = ch & 7;
      int sb = cbs ^ (row & 7);
      gload16(Kb + (size_t)(bh * 2048 + t0 + row) * 64 + sb * 8,
              &Ks[buf][(w * 128 + i * 64) * 8]);
      gload16(Vt + (size_t)(bh * 64 + row) * 2048 + t0 + sb * 8,
              &Vs[buf][(w * 128 + i * 64) * 8]);
    }
  };

  stageKV(0, 0);
  __syncthreads();

  for (int t = 0; t < 32; ++t) {
    int buf = t & 1;
    if (t + 1 < 32) stageKV(buf ^ 1, (t + 1) * 64);

    // ---- S^T = K * Q^T ----
    const short* Kbuf = &Ks[buf][0];
    short8 kf0[4], kf1[4];
#pragma unroll
    for (int mi = 0; mi < 4; ++mi) {
      kf0[mi] = *(const short8*)&Kbuf[koff[mi][0]];
      kf1[mi] = *(const short8*)&Kbuf[koff[mi][1]];
    }
    f32x4 sacc[4][2];  // [mi][qi]
    __builtin_amdgcn_s_setprio(1);
#pragma unroll
    for (int mi = 0; mi < 4; ++mi)
#pragma unroll
      for (int qi = 0; qi < 2; ++qi)
        sacc[mi][qi] = __builtin_amdgcn_mfma_f32_16x16x32_bf16(kf0[mi], qf[qi][0], z4, 0, 0, 0);
#pragma unroll
    for (int mi = 0; mi < 4; ++mi)
#pragma unroll
      for (int qi = 0; qi < 2; ++qi)
        sacc[mi][qi] = __builtin_amdgcn_mfma_f32_16x16x32_bf16(kf1[mi], qf[qi][1], sacc[mi][qi], 0, 0, 0);
    __builtin_amdgcn_s_setprio(0);

    // ---- per-lane max via max3 trees ----
    float mx[2];
#pragma unroll
    for (int qi = 0; qi < 2; ++qi) {
      float t0v = max3f(sacc[0][qi][0], sacc[0][qi][1], sacc[0][qi][2]);
      float t1v = max3f(sacc[0][qi][3], sacc[1][qi][0], sacc[1][qi][1]);
      float t2v = max3f(sacc[1][qi][2], sacc[1][qi][3], sacc[2][qi][0]);
      float t3v = max3f(sacc[2][qi][1], sacc[2][qi][2], sacc[2][qi][3]);
      float t4v = max3f(sacc[3][qi][0], sacc[3][qi][1], sacc[3][qi][2]);
      mx[qi] = fmaxf(max3f(max3f(t0v, t1v, t2v), t3v, t4v), sacc[3][qi][3]);
    }
    // defer-max: rescale only when some lane's local max outgrows mrun by THR=8
    bool grow = (mx[0] > mrun[0] + 8.f) || (mx[1] > mrun[1] + 8.f);
    if (__any(grow)) {
#pragma unroll
      for (int qi = 0; qi < 2; ++qi) {
        float a = mx[qi];
        a = fmaxf(a, __shfl_xor(a, 16));
        a = fmaxf(a, __shfl_xor(a, 32));
        float mnew = fmaxf(mrun[qi], a);
        float f = __builtin_amdgcn_exp2f(mrun[qi] - mnew);
        lrun[qi] *= f;
        mrun[qi] = mnew;
#pragma unroll
        for (int ei = 0; ei < 4; ++ei)
#pragma unroll
          for (int r = 0; r < 4; ++r) oacc[ei][qi][r] *= f;
      }
    }

    // ---- P = exp2(S - mrun), per-lane partial sums, pack to bf16 ----
    short8 pf[2][2];  // [qi][ks]
#pragma unroll
    for (int qi = 0; qi < 2; ++qi) {
      float p[4][4];
#pragma unroll
      for (int mi = 0; mi < 4; ++mi)
#pragma unroll
        for (int r = 0; r < 4; ++r)
          p[mi][r] = __builtin_amdgcn_exp2f(sacc[mi][qi][r] - mrun[qi]);
      float s0 = (p[0][0] + p[0][1]) + (p[0][2] + p[0][3]);
      float s1 = (p[1][0] + p[1][1]) + (p[1][2] + p[1][3]);
      float s2 = (p[2][0] + p[2][1]) + (p[2][2] + p[2][3]);
      float s3 = (p[3][0] + p[3][1]) + (p[3][2] + p[3][3]);
      lrun[qi] += (s0 + s1) + (s2 + s3);
#pragma unroll
      for (int ks = 0; ks < 2; ++ks) {
        union { uint32_t w[4]; short8 s; } pu;
        asm("v_cvt_pk_bf16_f32 %0, %1, %2" : "=v"(pu.w[0]) : "v"(p[ks * 2][0]), "v"(p[ks * 2][1]));
        asm("v_cvt_pk_bf16_f32 %0, %1, %2" : "=v"(pu.w[1]) : "v"(p[ks * 2][2]), "v"(p[ks * 2][3]));
        asm("v_cvt_pk_bf16_f32 %0, %1, %2" : "=v"(pu.w[2]) : "v"(p[ks * 2 + 1][0]), "v"(p[ks * 2 + 1][1]));
        asm("v_cvt_pk_bf16_f32 %0, %1, %2" : "=v"(pu.w[3]) : "v"(p[ks * 2 + 1][2]), "v"(p[ks * 2 + 1][3]));
        pf[qi][ks] = pu.s;
      }
    }

    // ---- PV: att^T[e][q] += V^T-frag (k-permuted) * P-frag ----
    const short* Vbuf = &Vs[buf][0];
    __builtin_amdgcn_s_setprio(1);
#pragma unroll
    for (int ks = 0; ks < 2; ++ks)
#pragma unroll
      for (int ei = 0; ei < 4; ++ei) {
        short4v v0 = *(const short4v*)&Vbuf[voff[ks][ei][0]];
        short4v v1 = *(const short4v*)&Vbuf[voff[ks][ei][1]];
        short8 vf = {v0[0], v0[1], v0[2], v0[3], v1[0], v1[1], v1[2], v1[3]};
#pragma unroll
        for (int qi = 0; qi < 2; ++qi)
          oacc[ei][qi] = __builtin_amdgcn_mfma_f32_16x16x32_bf16(vf, pf[qi][ks], oacc[ei][qi], 0, 0, 0);
      }
    __builtin_amdgcn_s_setprio(0);

    __syncthreads();
  }

  // ---- epilogue: reduce lrun across lanes once, normalize, store ----
  int b = bh >> 4, h = bh & 15;
#pragma unroll
  for (int qi = 0; qi < 2; ++qi) {
    float lt = lrun[qi];
    lt += __shfl_xor(lt, 16);
    lt += __shfl_xor(lt, 32);
    float inv = 1.0f / lt;
    int s = q0 + qi * 16 + c;
#pragma unroll
    for (int ei = 0; ei < 4; ++ei) {
      short4v o;
#pragma unroll
      for (int r = 0; r < 4; ++r) o[r] = bf16r(oacc[ei][qi][r] * inv);
      *(short4v*)&attb[(size_t)(b * 2048 + s) * 1024 + h * 64 + ei * 16 + g * 4] = o;
    }
  }
}

extern "C" void kernel_launch(void* const* d_in, const int* in_sizes, int n_in,
                              void* d_out, int out_size, void* d_ws, size_t ws_size,
                              hipStream_t stream) {
  const float* x  = (const float*)d_in[0];
  const float* wq = (const float*)d_in[1];
  const float* bq = (const float*)d_in[2];
  const float* wk = (const float*)d_in[3];
  const float* bk = (const float*)d_in[4];
  const float* wv = (const float*)d_in[5];
  const float* bv = (const float*)d_in[6];
  const float* wo = (const float*)d_in[7];
  const float* bo = (const float*)d_in[8];
  float* out = (float*)d_out;

  uint8_t* ws = (uint8_t*)d_ws;
  short* xb  = (short*)(ws);                  // 16 MB: x bf16 (reused as att after QKV GEMM)
  short* wt  = (short*)(ws + (16u << 20));    // 6 MB : Wt_qkv
  short* wob = (short*)(ws + (22u << 20));    // 2 MB : wo bf16
  short* qb  = (short*)(ws + (24u << 20));    // 16 MB: Q (scaled) [bh][s][64]
  short* kb  = (short*)(ws + (40u << 20));    // 16 MB: K [bh][s][64]
  short* vb  = (short*)(ws + (56u << 20));    // 16 MB: V [bh][s][64]
  short* vtb = (short*)(ws + (72u << 20));    // 16 MB: V^T [bh][64][2048]
  short* attb = xb;

  k_cvt<<<8192, 256, 0, stream>>>(x, xb, 2097152);
  k_cvt<<<1024, 256, 0, stream>>>(wo, wob, 262144);
  k_cvt_wt<<<dim3(16, 16, 3), 256, 0, stream>>>(wq, wk, wv, wt);
  k_gemm<0><<<dim3(24, 64), 256, 0, stream>>>(xb, wt, bq, bk, bv, qb, kb, vb, nullptr);
  k_vt<<<dim3(32, 64), 256, 0, stream>>>(vb, vtb);
  k_attn<<<dim3(16, 64), 256, 0, stream>>>(qb, kb, vtb, attb);
  k_gemm<1><<<dim3(8, 64), 256, 0, stream>>>(attb, wob, bo, nullptr, nullptr,
                                             nullptr, nullptr, nullptr, out);
}